// Round 1
// baseline (659.032 us; speedup 1.0000x reference)
//
#include <hip/hip_runtime.h>
#include <stdint.h>

// Problem constants (from reference):
// x: [1,4,72,72,72] fp32 -> x4: [4,72,5184]
// attentions: [1,4,4608,4608] fp32
// P=9, nH=8, nW=576, L=4608, P*P=81
#define PSZ    9
#define CH     4
#define LROWS  4608   // L (also the GEMM K dim)
#define NWp    576
#define HPdim  72
#define WPdim  5184
#define NPAD   96     // 81 padded to 6 tiles of 16
#define NVALID 81

typedef short s16x8 __attribute__((ext_vector_type(8)));
typedef float f32x4 __attribute__((ext_vector_type(4)));

__device__ __forceinline__ short f2bf(float f) {
    uint32_t u = __builtin_bit_cast(uint32_t, f);
    u += 0x8000u;                 // round-to-nearest (half away); fine for this tolerance
    return (short)(u >> 16);
}

// Kernel 1: build patches in bf16, layout pb[c][n][m], n padded to 96 (pad rows = 0).
// patches[c, n=ki*9+kj, m=bi*576+bj] = x4[c, bi*9+ki, bj*9+kj]
__global__ __launch_bounds__(256) void build_pb_kernel(
    const float* __restrict__ x, uint16_t* __restrict__ pb)
{
    int tid = blockIdx.x * 256 + threadIdx.x;   // total CH*NPAD*LROWS
    int m  = tid % LROWS;
    int cn = tid / LROWS;
    int n  = cn % NPAD;
    int c  = cn / NPAD;
    uint16_t v = 0;
    if (n < NVALID) {
        int ki = n / PSZ, kj = n % PSZ;
        int bi = m / NWp, bj = m % NWp;
        float f = x[(size_t)(c * HPdim + bi * PSZ + ki) * WPdim + bj * PSZ + kj];
        uint32_t u = __builtin_bit_cast(uint32_t, f);
        u += 0x8000u;
        v = (uint16_t)(u >> 16);
    }
    pb[tid] = v;
}

// Kernel 2: per-wave 16(l) x 96(n) MFMA tile, K-loop over m (4608), streaming attn
// fp32 -> bf16 in registers, counting nonzeros on the fly; fused normalize +
// fold + x*(1+corr) + leaky_relu epilogue with scattered fp32 stores.
__global__ __launch_bounds__(256) void cross_gemm_kernel(
    const float* __restrict__ x,
    const float* __restrict__ attn,
    const uint16_t* __restrict__ pb,
    float* __restrict__ out)
{
    const int lane = threadIdx.x & 63;
    const int widx = threadIdx.x >> 6;
    const int wave = blockIdx.x * 4 + widx;   // 0..1151
    const int c    = wave / 288;              // 288 row-tiles per channel
    const int tile = wave - c * 288;
    const int r0   = tile * 16;
    const int li   = lane & 15;
    const int quad = lane >> 4;

    // A: lane holds attn row (r0+li), k-slice quad*8..+8 (8 contiguous fp32)
    const float* aptr = attn + (size_t)(c * LROWS + r0 + li) * LROWS + quad * 8;
    // B: lane holds pb row n = 16*t + li, same k-slice (8 contiguous bf16)
    const uint16_t* bptr = pb + (size_t)(c * NPAD + li) * LROWS + quad * 8;

    f32x4 acc[6];
#pragma unroll
    for (int t = 0; t < 6; ++t) acc[t] = (f32x4){0.f, 0.f, 0.f, 0.f};

    int cnt = 0;
    const int ITERS = LROWS / 32;   // 144

    // prefetch iteration 0
    float4 a0 = *(const float4*)(aptr);
    float4 a1 = *(const float4*)(aptr + 4);
    s16x8 b[6];
#pragma unroll
    for (int t = 0; t < 6; ++t)
        b[t] = *(const s16x8*)(bptr + t * 16 * LROWS);

    for (int it = 0; it < ITERS; ++it) {
        // prefetch next (clamped re-load of last iter at the tail; values unused)
        const int itn = (it + 1 < ITERS) ? (it + 1) : it;
        const float*    ap = aptr + itn * 32;
        const uint16_t* bp = bptr + itn * 32;
        float4 na0 = *(const float4*)(ap);
        float4 na1 = *(const float4*)(ap + 4);
        s16x8 nb[6];
#pragma unroll
        for (int t = 0; t < 6; ++t)
            nb[t] = *(const s16x8*)(bp + t * 16 * LROWS);

        // count nonzeros on the fp32 values (each attn element seen exactly once)
        cnt += (a0.x != 0.f) + (a0.y != 0.f) + (a0.z != 0.f) + (a0.w != 0.f)
             + (a1.x != 0.f) + (a1.y != 0.f) + (a1.z != 0.f) + (a1.w != 0.f);

        // convert A to bf16 fragment (j = k-within-slice order matches memory order)
        s16x8 af;
        af[0] = f2bf(a0.x); af[1] = f2bf(a0.y); af[2] = f2bf(a0.z); af[3] = f2bf(a0.w);
        af[4] = f2bf(a1.x); af[5] = f2bf(a1.y); af[6] = f2bf(a1.z); af[7] = f2bf(a1.w);

#pragma unroll
        for (int t = 0; t < 6; ++t)
            acc[t] = __builtin_amdgcn_mfma_f32_16x16x32_bf16(af, b[t], acc[t], 0, 0, 0);

        a0 = na0; a1 = na1;
#pragma unroll
        for (int t = 0; t < 6; ++t) b[t] = nb[t];
    }

    // Reduce nonzero counts: row (r0+i) partials live in lanes i, i+16, i+32, i+48
    cnt += __shfl_down(cnt, 32);
    cnt += __shfl_down(cnt, 16);
    // lanes 0..15 now hold the full count for rows r0+0..r0+15

    // Epilogue: C/D layout col = lane&15 (n within tile), row = quad*4 + reg (l within tile)
#pragma unroll
    for (int reg = 0; reg < 4; ++reg) {
        const int lrow  = quad * 4 + reg;                 // 0..15
        const int cnt_r = __shfl(cnt, lrow);              // broadcast from lane 'lrow'
        const float scale = 1.0f / ((float)cnt_r + 1e-5f);
        const int l  = r0 + lrow;
        const int bi = l / NWp;
        const int bj = l - bi * NWp;
#pragma unroll
        for (int t = 0; t < 6; ++t) {
            const int n = t * 16 + li;
            if (n < NVALID) {
                const int ki = n / PSZ, kj = n - (n / PSZ) * PSZ;
                const size_t idx = (size_t)(c * HPdim + bi * PSZ + ki) * WPdim
                                 + (size_t)(bj * PSZ + kj);
                const float xv = x[idx];
                const float o  = xv * (1.0f + acc[t][reg] * scale);
                out[idx] = (o > 0.f) ? o : 0.2f * o;
            }
        }
    }
}

extern "C" void kernel_launch(void* const* d_in, const int* in_sizes, int n_in,
                              void* d_out, int out_size, void* d_ws, size_t ws_size,
                              hipStream_t stream)
{
    const float* x    = (const float*)d_in[0];
    const float* attn = (const float*)d_in[1];
    float* out        = (float*)d_out;
    uint16_t* pb      = (uint16_t*)d_ws;   // CH*NPAD*LROWS bf16 = 3.5 MB

    const int total_pb = CH * NPAD * LROWS;           // 1,769,472
    build_pb_kernel<<<total_pb / 256, 256, 0, stream>>>(x, pb);
    cross_gemm_kernel<<<288, 256, 0, stream>>>(x, attn, pb, out);
}

// Round 2
// 574.662 us; speedup vs baseline: 1.1468x; 1.1468x over previous
//
#include <hip/hip_runtime.h>
#include <stdint.h>

// Problem constants (from reference):
// x: [1,4,72,72,72] fp32 -> x4: [4,72,5184]
// attentions: [1,4,4608,4608] fp32
// P=9, nH=8, nW=576, L=4608, P*P=81
#define PSZ    9
#define CH     4
#define LROWS  4608   // L (also the GEMM K dim)
#define NWp    576
#define HPdim  72
#define WPdim  5184
#define NPAD   96     // 81 padded to 6 tiles of 16
#define NVALID 81
#define KSPLIT 4
#define KSEG   (LROWS / KSPLIT)   // 1152

typedef short s16x8 __attribute__((ext_vector_type(8)));
typedef float f32x4 __attribute__((ext_vector_type(4)));

__device__ __forceinline__ short f2bf(float f) {
    uint32_t u = __builtin_bit_cast(uint32_t, f);
    u += 0x8000u;                 // round-to-nearest (half away)
    return (short)(u >> 16);
}

// Kernel 1: build patches in bf16, layout pb[c][n][m], n padded to 96 (pad rows = 0).
// patches[c, n=ki*9+kj, m=bi*576+bj] = x4[c, bi*9+ki, bj*9+kj]
__global__ __launch_bounds__(256) void build_pb_kernel(
    const float* __restrict__ x, uint16_t* __restrict__ pb)
{
    int tid = blockIdx.x * 256 + threadIdx.x;   // total CH*NPAD*LROWS
    int m  = tid % LROWS;
    int cn = tid / LROWS;
    int n  = cn % NPAD;
    int c  = cn / NPAD;
    uint16_t v = 0;
    if (n < NVALID) {
        int ki = n / PSZ, kj = n % PSZ;
        int bi = m / NWp, bj = m % NWp;
        float f = x[(size_t)(c * HPdim + bi * PSZ + ki) * WPdim + bj * PSZ + kj];
        uint32_t u = __builtin_bit_cast(uint32_t, f);
        u += 0x8000u;
        v = (uint16_t)(u >> 16);
    }
    pb[tid] = v;
}

// Kernel 2: one block per 16(l) x 96(n) output tile; the block's 4 waves split
// the K dim (4608) into 4 segments of 1152, each streaming its attn slice
// fp32->bf16 in registers with MFMA accumulation + nonzero counting. LDS
// reduction across waves, then wave 0 runs the fused normalize + fold +
// x*(1+corr) + leaky_relu epilogue.
__global__ __launch_bounds__(256) void cross_gemm_kernel(
    const float* __restrict__ x,
    const float* __restrict__ attn,
    const uint16_t* __restrict__ pb,
    float* __restrict__ out)
{
    __shared__ float red[KSPLIT - 1][64][25];   // stride 25: coprime with 32 banks
    __shared__ int   cshared[KSPLIT][16];

    const int lane = threadIdx.x & 63;
    const int widx = threadIdx.x >> 6;
    const int blk  = blockIdx.x;              // 0..1151
    const int c    = blk / 288;               // 288 row-tiles per channel
    const int tile = blk - c * 288;
    const int r0   = tile * 16;
    const int li   = lane & 15;
    const int quad = lane >> 4;
    const int k0   = widx * KSEG;

    // A: lane holds attn row (r0+li), k-slice k0 + quad*8 (8 contiguous fp32)
    const float* aptr = attn + (size_t)(c * LROWS + r0 + li) * LROWS + k0 + quad * 8;
    // B: lane holds pb row n = 16*t + li, same k-slice (8 contiguous bf16)
    const uint16_t* bptr = pb + (size_t)(c * NPAD + li) * LROWS + k0 + quad * 8;

    f32x4 acc[6];
#pragma unroll
    for (int t = 0; t < 6; ++t) acc[t] = (f32x4){0.f, 0.f, 0.f, 0.f};

    int cnt = 0;
    const int ITERS = KSEG / 32;   // 36

    // prefetch iteration 0
    float4 a0 = *(const float4*)(aptr);
    float4 a1 = *(const float4*)(aptr + 4);
    s16x8 b[6];
#pragma unroll
    for (int t = 0; t < 6; ++t)
        b[t] = *(const s16x8*)(bptr + t * 16 * LROWS);

    for (int it = 0; it < ITERS; ++it) {
        // prefetch next (clamped re-load at the tail; values unused)
        const int itn = (it + 1 < ITERS) ? (it + 1) : it;
        const float*    ap = aptr + itn * 32;
        const uint16_t* bp = bptr + itn * 32;
        float4 na0 = *(const float4*)(ap);
        float4 na1 = *(const float4*)(ap + 4);
        s16x8 nb[6];
#pragma unroll
        for (int t = 0; t < 6; ++t)
            nb[t] = *(const s16x8*)(bp + t * 16 * LROWS);

        // count nonzeros on fp32 values (each attn element seen exactly once)
        cnt += (a0.x != 0.f) + (a0.y != 0.f) + (a0.z != 0.f) + (a0.w != 0.f)
             + (a1.x != 0.f) + (a1.y != 0.f) + (a1.z != 0.f) + (a1.w != 0.f);

        s16x8 af;
        af[0] = f2bf(a0.x); af[1] = f2bf(a0.y); af[2] = f2bf(a0.z); af[3] = f2bf(a0.w);
        af[4] = f2bf(a1.x); af[5] = f2bf(a1.y); af[6] = f2bf(a1.z); af[7] = f2bf(a1.w);

#pragma unroll
        for (int t = 0; t < 6; ++t)
            acc[t] = __builtin_amdgcn_mfma_f32_16x16x32_bf16(af, b[t], acc[t], 0, 0, 0);

        a0 = na0; a1 = na1;
#pragma unroll
        for (int t = 0; t < 6; ++t) b[t] = nb[t];
    }

    // Per-wave nonzero reduction: row (r0+i) partials in lanes i, i+16, i+32, i+48
    cnt += __shfl_down(cnt, 32);
    cnt += __shfl_down(cnt, 16);
    if (lane < 16) cshared[widx][lane] = cnt;

    // Waves 1..3 publish their accumulators
    if (widx > 0) {
#pragma unroll
        for (int t = 0; t < 6; ++t)
#pragma unroll
            for (int r = 0; r < 4; ++r)
                red[widx - 1][lane][t * 4 + r] = acc[t][r];
    }
    __syncthreads();

    if (widx == 0) {
        // Epilogue: C/D layout col = lane&15 (n), row = quad*4 + reg (l)
#pragma unroll
        for (int reg = 0; reg < 4; ++reg) {
            const int lrow = quad * 4 + reg;              // 0..15
            const int cnt_r = cshared[0][lrow] + cshared[1][lrow]
                            + cshared[2][lrow] + cshared[3][lrow];
            const float scale = 1.0f / ((float)cnt_r + 1e-5f);
            const int l  = r0 + lrow;
            const int bi = l / NWp;
            const int bj = l - bi * NWp;
#pragma unroll
            for (int t = 0; t < 6; ++t) {
                const int n = t * 16 + li;
                if (n < NVALID) {
                    const float v = acc[t][reg]
                                  + red[0][lane][t * 4 + reg]
                                  + red[1][lane][t * 4 + reg]
                                  + red[2][lane][t * 4 + reg];
                    const int ki = n / PSZ, kj = n - (n / PSZ) * PSZ;
                    const size_t idx = (size_t)(c * HPdim + bi * PSZ + ki) * WPdim
                                     + (size_t)(bj * PSZ + kj);
                    const float xv = x[idx];
                    const float o  = xv * (1.0f + v * scale);
                    out[idx] = (o > 0.f) ? o : 0.2f * o;
                }
            }
        }
    }
}

extern "C" void kernel_launch(void* const* d_in, const int* in_sizes, int n_in,
                              void* d_out, int out_size, void* d_ws, size_t ws_size,
                              hipStream_t stream)
{
    const float* x    = (const float*)d_in[0];
    const float* attn = (const float*)d_in[1];
    float* out        = (float*)d_out;
    uint16_t* pb      = (uint16_t*)d_ws;   // CH*NPAD*LROWS bf16 = 3.5 MB

    const int total_pb = CH * NPAD * LROWS;           // 1,769,472
    build_pb_kernel<<<total_pb / 256, 256, 0, stream>>>(x, pb);
    cross_gemm_kernel<<<CH * 288, 256, 0, stream>>>(x, attn, pb, out);
}

// Round 3
// 504.155 us; speedup vs baseline: 1.3072x; 1.1399x over previous
//
#include <hip/hip_runtime.h>
#include <stdint.h>

// Problem constants (from reference):
// x: [1,4,72,72,72] fp32 -> x4: [4,72,5184]
// attentions: [1,4,4608,4608] fp32
// P=9, nH=8, nW=576, L=4608, P*P=81
#define PSZ    9
#define CH     4
#define LROWS  4608   // L (also the GEMM K dim)
#define NWp    576
#define HPdim  72
#define WPdim  5184
#define NPAD   96     // 81 padded to 6 tiles of 16
#define NVALID 81
#define KSPLIT 4
#define KSEG   (LROWS / KSPLIT)   // 1152
#define KBLK   32                 // k per B chunk
#define NKB    (LROWS / KBLK)     // 144

typedef short s16x8 __attribute__((ext_vector_type(8)));
typedef float f32x4 __attribute__((ext_vector_type(4)));

__device__ __forceinline__ uint16_t f2bf(float f) {
    uint32_t u = __builtin_bit_cast(uint32_t, f);
    u += 0x8000u;                 // round-to-nearest (half away)
    return (uint16_t)(u >> 16);
}

// Kernel 1: build patches bf16 in layout pb[c][kb][n(96)][ks(32)], i.e.
// pb[((c*144+kb)*96+n)*32+ks] = bf16(patches[c][n][m=kb*32+ks]),
// patches[c, n=ki*9+kj, m=bi*576+bj] = x4[c, bi*9+ki, bj*9+kj].
// One block per (c,kb): all 32 m share bi=kb/18; bj0=(kb%18)*32.
// Stage the 9x288 fp32 x-slab in LDS (coalesced rows), emit 96x32 bf16.
__global__ __launch_bounds__(256) void build_pb_kernel(
    const float* __restrict__ x, uint16_t* __restrict__ pb)
{
    __shared__ float xs[PSZ][288];
    const int blk = blockIdx.x;            // 0..575
    const int c   = blk / NKB;
    const int kb  = blk - c * NKB;
    const int bi  = kb / 18;
    const int bj0 = (kb - bi * 18) * KBLK; // multiple of 32

    const float* src = x + (size_t)(c * HPdim + bi * PSZ) * WPdim + bj0 * PSZ;
    for (int idx = threadIdx.x; idx < PSZ * 288; idx += 256) {
        int r = idx / 288, col = idx - r * 288;
        xs[r][col] = src[(size_t)r * WPdim + col];
    }
    __syncthreads();

    uint16_t* dst = pb + (size_t)(c * NKB + kb) * NPAD * KBLK;
    for (int oidx = threadIdx.x; oidx < NPAD * KBLK; oidx += 256) {
        int n = oidx / KBLK, ks = oidx - n * KBLK;
        uint16_t v = 0;
        if (n < NVALID) {
            int ki = n / PSZ, kj = n - ki * PSZ;
            v = f2bf(xs[ki][ks * PSZ + kj]);
        }
        dst[oidx] = v;
    }
}

// Kernel 2: one block per 16(l) x 96(n) output tile; 4 waves split K (4608)
// into 4 segments of 1152. Stream attn fp32->bf16 in registers with MFMA
// accumulation + nonzero counting; B fragments come from the [kb][n][ks]
// layout as fully-coalesced contiguous 1KB loads. LDS cross-wave reduction,
// wave 0 runs the fused normalize + fold + x*(1+corr) + leaky_relu epilogue.
__global__ __launch_bounds__(256) void cross_gemm_kernel(
    const float* __restrict__ x,
    const float* __restrict__ attn,
    const uint16_t* __restrict__ pb,
    float* __restrict__ out)
{
    __shared__ float red[KSPLIT - 1][64][25];   // stride 25: conflict-free
    __shared__ int   cshared[KSPLIT][16];

    const int lane = threadIdx.x & 63;
    const int widx = threadIdx.x >> 6;
    const int blk  = blockIdx.x;              // 0..1151
    const int c    = blk / 288;               // 288 row-tiles per channel
    const int tile = blk - c * 288;
    const int r0   = tile * 16;
    const int li   = lane & 15;
    const int quad = lane >> 4;
    const int k0   = widx * KSEG;
    const int kb0  = k0 / KBLK;               // widx*36

    // A: lane holds attn row (r0+li), k-slice k0 + quad*8 (8 contiguous fp32)
    const float* aptr = attn + (size_t)(c * LROWS + r0 + li) * LROWS + k0 + quad * 8;
    // B: per iter it (kb = kb0+it), per t: contiguous 1KB chunk
    //   addr = pbB + kb*96*32 + (16t+li)*32 + quad*8   (elements)
    const uint16_t* bbase = pb + (size_t)(c * NKB + kb0) * NPAD * KBLK
                          + li * KBLK + quad * 8;

    f32x4 acc[6];
#pragma unroll
    for (int t = 0; t < 6; ++t) acc[t] = (f32x4){0.f, 0.f, 0.f, 0.f};

    int cnt = 0;
    const int ITERS = KSEG / 32;   // 36

    // prefetch iteration 0
    float4 a0 = *(const float4*)(aptr);
    float4 a1 = *(const float4*)(aptr + 4);
    s16x8 b[6];
#pragma unroll
    for (int t = 0; t < 6; ++t)
        b[t] = *(const s16x8*)(bbase + t * 16 * KBLK);

    for (int it = 0; it < ITERS; ++it) {
        // prefetch next (clamped re-load at the tail; values unused)
        const int itn = (it + 1 < ITERS) ? (it + 1) : it;
        const float*    ap = aptr + itn * 32;
        const uint16_t* bp = bbase + (size_t)itn * NPAD * KBLK;
        float4 na0 = *(const float4*)(ap);
        float4 na1 = *(const float4*)(ap + 4);
        s16x8 nb[6];
#pragma unroll
        for (int t = 0; t < 6; ++t)
            nb[t] = *(const s16x8*)(bp + t * 16 * KBLK);

        // count nonzeros on fp32 values (each attn element seen exactly once)
        cnt += (a0.x != 0.f) + (a0.y != 0.f) + (a0.z != 0.f) + (a0.w != 0.f)
             + (a1.x != 0.f) + (a1.y != 0.f) + (a1.z != 0.f) + (a1.w != 0.f);

        s16x8 af;
        af[0] = f2bf(a0.x); af[1] = f2bf(a0.y); af[2] = f2bf(a0.z); af[3] = f2bf(a0.w);
        af[4] = f2bf(a1.x); af[5] = f2bf(a1.y); af[6] = f2bf(a1.z); af[7] = f2bf(a1.w);

#pragma unroll
        for (int t = 0; t < 6; ++t)
            acc[t] = __builtin_amdgcn_mfma_f32_16x16x32_bf16(af, b[t], acc[t], 0, 0, 0);

        a0 = na0; a1 = na1;
#pragma unroll
        for (int t = 0; t < 6; ++t) b[t] = nb[t];
    }

    // Per-wave nonzero reduction: row (r0+i) partials in lanes i, i+16, i+32, i+48
    cnt += __shfl_down(cnt, 32);
    cnt += __shfl_down(cnt, 16);
    if (lane < 16) cshared[widx][lane] = cnt;

    // Waves 1..3 publish their accumulators
    if (widx > 0) {
#pragma unroll
        for (int t = 0; t < 6; ++t)
#pragma unroll
            for (int r = 0; r < 4; ++r)
                red[widx - 1][lane][t * 4 + r] = acc[t][r];
    }
    __syncthreads();

    if (widx == 0) {
        // Epilogue: C/D layout col = lane&15 (n), row = quad*4 + reg (l)
#pragma unroll
        for (int reg = 0; reg < 4; ++reg) {
            const int lrow = quad * 4 + reg;              // 0..15
            const int cnt_r = cshared[0][lrow] + cshared[1][lrow]
                            + cshared[2][lrow] + cshared[3][lrow];
            const float scale = 1.0f / ((float)cnt_r + 1e-5f);
            const int l  = r0 + lrow;
            const int bi = l / NWp;
            const int bj = l - bi * NWp;
#pragma unroll
            for (int t = 0; t < 6; ++t) {
                const int n = t * 16 + li;
                if (n < NVALID) {
                    const float v = acc[t][reg]
                                  + red[0][lane][t * 4 + reg]
                                  + red[1][lane][t * 4 + reg]
                                  + red[2][lane][t * 4 + reg];
                    const int ki = n / PSZ, kj = n - (n / PSZ) * PSZ;
                    const size_t idx = (size_t)(c * HPdim + bi * PSZ + ki) * WPdim
                                     + (size_t)(bj * PSZ + kj);
                    const float xv = x[idx];
                    const float o  = xv * (1.0f + v * scale);
                    out[idx] = (o > 0.f) ? o : 0.2f * o;
                }
            }
        }
    }
}

extern "C" void kernel_launch(void* const* d_in, const int* in_sizes, int n_in,
                              void* d_out, int out_size, void* d_ws, size_t ws_size,
                              hipStream_t stream)
{
    const float* x    = (const float*)d_in[0];
    const float* attn = (const float*)d_in[1];
    float* out        = (float*)d_out;
    uint16_t* pb      = (uint16_t*)d_ws;   // CH*NKB*NPAD*KBLK bf16 = 3.5 MB

    build_pb_kernel<<<CH * NKB, 256, 0, stream>>>(x, pb);
    cross_gemm_kernel<<<CH * 288, 256, 0, stream>>>(x, attn, pb, out);
}

// Round 5
// 497.383 us; speedup vs baseline: 1.3250x; 1.0136x over previous
//
#include <hip/hip_runtime.h>
#include <hip/hip_bf16.h>
#include <stdint.h>

// Problem constants (from reference):
// x: [1,4,72,72,72] fp32 -> x4: [4,72,5184]
// attentions: [1,4,4608,4608] fp32
// P=9, nH=8, nW=576, L=4608, P*P=81
#define PSZ    9
#define CH     4
#define LROWS  4608   // L (also the GEMM K dim)
#define NWp    576
#define HPdim  72
#define WPdim  5184
#define NPAD   96     // 81 padded to 6 tiles of 16
#define NVALID 81
#define KSPLIT 4
#define KSEG   (LROWS / KSPLIT)   // 1152
#define KBLK   32                 // k per B chunk
#define NKB    (LROWS / KBLK)     // 144
#define BCH    (NPAD * KBLK)      // 3072 elements per (kb) B chunk

typedef short s16x8 __attribute__((ext_vector_type(8)));
typedef float f32x4 __attribute__((ext_vector_type(4)));

__device__ __forceinline__ uint16_t f2bf(float f) {
    uint32_t u = __builtin_bit_cast(uint32_t, f);
    u += 0x8000u;
    return (uint16_t)(u >> 16);
}

// Packed fp32x8 -> bf16x8 fragment (v_cvt_pk_bf16_f32, RNE)
__device__ __forceinline__ s16x8 cvt8(float4 a, float4 b) {
    union { s16x8 v; uint32_t u[4]; } r;
    __hip_bfloat162 h0 = __float22bfloat162_rn(make_float2(a.x, a.y));
    __hip_bfloat162 h1 = __float22bfloat162_rn(make_float2(a.z, a.w));
    __hip_bfloat162 h2 = __float22bfloat162_rn(make_float2(b.x, b.y));
    __hip_bfloat162 h3 = __float22bfloat162_rn(make_float2(b.z, b.w));
    __builtin_memcpy(&r.u[0], &h0, 4);
    __builtin_memcpy(&r.u[1], &h1, 4);
    __builtin_memcpy(&r.u[2], &h2, 4);
    __builtin_memcpy(&r.u[3], &h3, 4);
    return r.v;
}

__device__ __forceinline__ int count8(float4 a, float4 b) {
    return (a.x != 0.f) + (a.y != 0.f) + (a.z != 0.f) + (a.w != 0.f)
         + (b.x != 0.f) + (b.y != 0.f) + (b.z != 0.f) + (b.w != 0.f);
}

// Kernel 1: build patches bf16 in layout pb[c][kb][n(96)][ks(32)].
// pb[((c*144+kb)*96+n)*32+ks] = bf16(patches[c][n][m=kb*32+ks]),
// patches[c, n=ki*9+kj, m=bi*576+bj] = x4[c, bi*9+ki, bj*9+kj].
__global__ __launch_bounds__(256) void build_pb_kernel(
    const float* __restrict__ x, uint16_t* __restrict__ pb)
{
    __shared__ float xs[PSZ][288];
    const int blk = blockIdx.x;            // 0..575
    const int c   = blk / NKB;
    const int kb  = blk - c * NKB;
    const int bi  = kb / 18;
    const int bj0 = (kb - bi * 18) * KBLK;

    const float* src = x + (size_t)(c * HPdim + bi * PSZ) * WPdim + bj0 * PSZ;
    for (int idx = threadIdx.x; idx < PSZ * 288; idx += 256) {
        int r = idx / 288, col = idx - r * 288;
        xs[r][col] = src[(size_t)r * WPdim + col];
    }
    __syncthreads();

    uint16_t* dst = pb + (size_t)(c * NKB + kb) * BCH;
    for (int oidx = threadIdx.x; oidx < BCH; oidx += 256) {
        int n = oidx / KBLK, ks = oidx - n * KBLK;
        uint16_t v = 0;
        if (n < NVALID) {
            int ki = n / PSZ, kj = n - ki * PSZ;
            v = f2bf(xs[ki][ks * PSZ + kj]);
        }
        dst[oidx] = v;
    }
}

// Kernel 2: one block per 16(l) x 96(n) tile; 4 waves K-split (1152 each).
// Register ping-pong double-buffer over two 32-k half-iters per loop trip:
// no register copies, loads of one set in flight while computing the other.
__global__ __launch_bounds__(256) void cross_gemm_kernel(
    const float* __restrict__ x,
    const float* __restrict__ attn,
    const uint16_t* __restrict__ pb,
    float* __restrict__ out)
{
    __shared__ float red[KSPLIT - 1][64][25];
    __shared__ int   cshared[KSPLIT][16];

    const int lane = threadIdx.x & 63;
    const int widx = threadIdx.x >> 6;
    const int blk  = blockIdx.x;              // 0..1151
    const int c    = blk / 288;
    const int tile = blk - c * 288;
    const int r0   = tile * 16;
    const int li   = lane & 15;
    const int quad = lane >> 4;
    const int k0   = widx * KSEG;
    const int kb0  = k0 / KBLK;               // widx*36

    const float* ap = attn + (size_t)(c * LROWS + r0 + li) * LROWS + k0 + quad * 8;
    const uint16_t* bp = pb + (size_t)(c * NKB + kb0) * BCH + li * KBLK + quad * 8;

    f32x4 acc[6];
#pragma unroll
    for (int t = 0; t < 6; ++t) acc[t] = (f32x4){0.f, 0.f, 0.f, 0.f};

    int cnt = 0;
    const int DITERS = KSEG / 64;   // 18

    // preload set0 (k = 0)
    float4 a00 = *(const float4*)(ap);
    float4 a01 = *(const float4*)(ap + 4);
    s16x8 b0[6];
#pragma unroll
    for (int t = 0; t < 6; ++t) b0[t] = *(const s16x8*)(bp + t * 16 * KBLK);

    for (int dit = 0; dit < DITERS; ++dit) {
        // issue set1 loads (k = 64*dit + 32) -- always in-segment
        const float*    ap1 = ap + 32;
        const uint16_t* bp1 = bp + BCH;
        float4 a10 = *(const float4*)(ap1);
        float4 a11 = *(const float4*)(ap1 + 4);
        s16x8 b1[6];
#pragma unroll
        for (int t = 0; t < 6; ++t) b1[t] = *(const s16x8*)(bp1 + t * 16 * KBLK);

        // compute set0
        cnt += count8(a00, a01);
        {
            s16x8 af = cvt8(a00, a01);
#pragma unroll
            for (int t = 0; t < 6; ++t)
                acc[t] = __builtin_amdgcn_mfma_f32_16x16x32_bf16(af, b0[t], acc[t], 0, 0, 0);
        }

        // advance; issue set0 loads for next trip (clamped on last -- wave-uniform)
        const bool last = (dit == DITERS - 1);
        ap = last ? ap : ap + 64;
        bp = last ? bp : bp + 2 * BCH;
        a00 = *(const float4*)(ap);
        a01 = *(const float4*)(ap + 4);
#pragma unroll
        for (int t = 0; t < 6; ++t) b0[t] = *(const s16x8*)(bp + t * 16 * KBLK);

        // compute set1
        cnt += count8(a10, a11);
        {
            s16x8 af = cvt8(a10, a11);
#pragma unroll
            for (int t = 0; t < 6; ++t)
                acc[t] = __builtin_amdgcn_mfma_f32_16x16x32_bf16(af, b1[t], acc[t], 0, 0, 0);
        }
    }
    // note: final clamped set0 reload is wasted work (one half-iter), values unused
    // because the loop exits; correctness unaffected (re-read of same addresses).

    // Per-wave nonzero reduction: row (r0+i) partials in lanes i, i+16, i+32, i+48
    // (count8 ran exactly once per distinct 32-k chunk of this wave's segment)
    cnt += __shfl_down(cnt, 32);
    cnt += __shfl_down(cnt, 16);
    if (lane < 16) cshared[widx][lane] = cnt;

    if (widx > 0) {
#pragma unroll
        for (int t = 0; t < 6; ++t)
#pragma unroll
            for (int r = 0; r < 4; ++r)
                red[widx - 1][lane][t * 4 + r] = acc[t][r];
    }
    __syncthreads();

    if (widx == 0) {
        // Epilogue: C/D layout col = lane&15 (n), row = quad*4 + reg (l)
#pragma unroll
        for (int reg = 0; reg < 4; ++reg) {
            const int lrow = quad * 4 + reg;
            const int cnt_r = cshared[0][lrow] + cshared[1][lrow]
                            + cshared[2][lrow] + cshared[3][lrow];
            const float scale = 1.0f / ((float)cnt_r + 1e-5f);
            const int l  = r0 + lrow;
            const int bi = l / NWp;
            const int bj = l - bi * NWp;
#pragma unroll
            for (int t = 0; t < 6; ++t) {
                const int n = t * 16 + li;
                if (n < NVALID) {
                    const float v = acc[t][reg]
                                  + red[0][lane][t * 4 + reg]
                                  + red[1][lane][t * 4 + reg]
                                  + red[2][lane][t * 4 + reg];
                    const int ki = n / PSZ, kj = n - (n / PSZ) * PSZ;
                    const size_t idx = (size_t)(c * HPdim + bi * PSZ + ki) * WPdim
                                     + (size_t)(bj * PSZ + kj);
                    const float xv = x[idx];
                    const float o  = xv * (1.0f + v * scale);
                    out[idx] = (o > 0.f) ? o : 0.2f * o;
                }
            }
        }
    }
}

extern "C" void kernel_launch(void* const* d_in, const int* in_sizes, int n_in,
                              void* d_out, int out_size, void* d_ws, size_t ws_size,
                              hipStream_t stream)
{
    const float* x    = (const float*)d_in[0];
    const float* attn = (const float*)d_in[1];
    float* out        = (float*)d_out;
    uint16_t* pb      = (uint16_t*)d_ws;   // CH*NKB*BCH bf16 = 3.5 MB

    build_pb_kernel<<<CH * NKB, 256, 0, stream>>>(x, pb);
    cross_gemm_kernel<<<CH * 288, 256, 0, stream>>>(x, attn, pb, out);
}